// Round 8
// baseline (531.558 us; speedup 1.0000x reference)
//
#include <hip/hip_runtime.h>
#include <hip/hip_bf16.h>
#include <hip/hip_cooperative_groups.h>

namespace cg = cooperative_groups;

#define G_ 2048
#define NPG_ 128
#define INC_ 151
#define HID_ 64
#define NNODES_ (G_ * NPG_)      // 262144
#define NEDGES_ 2097152

typedef __hip_bfloat16 bf16;
typedef short bf16x8v __attribute__((ext_vector_type(8)));
typedef float f32x4 __attribute__((ext_vector_type(4)));

static __device__ __forceinline__ short f2bs(float f) {
    __hip_bfloat16 b = __float2bfloat16(f);
    return __builtin_bit_cast(short, b);
}

// ---------------------------------------------------------------------------
// kSort (cooperative, 256 blocks x 256): the whole edge-preprocessing chain
// in one launch.
//   P0: per-block histogram of coarse bucket (= src>>10) -> bccount[b][256];
//       blocks 0..39 also convert W1 [151][64] fp32 -> Bt [64][160] bf16.
//   P1: column scan (bucket bk=bid) over the 256 blocks, in place; bucket
//       total -> totals[bk].
//   P2: every block redundantly scans totals -> cbase in LDS (block 0
//       persists cbase[0..256] for k3), then
//   P3: scatter u32 records ((s&1023)<<7 | dl) to coarse buckets in rbuf.
//       rec bits: [16:14]=g&7, [13:7]=sl, [6:0]=dl.
// ---------------------------------------------------------------------------
__global__ void __launch_bounds__(256) kSort(const int* __restrict__ ei,
                                             const float* __restrict__ W1,
                                             bf16* __restrict__ Bt,
                                             unsigned int* __restrict__ bccount,
                                             unsigned int* __restrict__ totals,
                                             unsigned int* __restrict__ cbase,
                                             unsigned int* __restrict__ rbuf) {
    __shared__ unsigned int A[256];
    __shared__ unsigned int Bb[256];
    const int tid = threadIdx.x;
    const int bid = blockIdx.x;
    cg::grid_group grid = cg::this_grid();

    // ---- P0: histogram (+ W1 prep on blocks 0..39) ----
    A[tid] = 0;
    __syncthreads();
    const int e0 = bid * 8192;
    for (int e = e0 + tid; e < e0 + 8192; e += 256)
        atomicAdd(&A[ei[e] >> 10], 1u);
    __syncthreads();
    bccount[bid * 256 + tid] = A[tid];
    if (bid < 40) {
        int i = bid * 256 + tid;          // 0..10239 == 64*160 exactly
        int n = i / 160, k = i - n * 160;
        float v = (k < 151) ? W1[k * 64 + n] : 0.f;
        Bt[i] = __float2bfloat16(v);
    }
    grid.sync();

    // ---- P1: per-bucket scan over blocks (bucket = bid) ----
    {
        unsigned int c = bccount[tid * 256 + bid];
        A[tid] = c;
        __syncthreads();
        for (int off = 1; off < 256; off <<= 1) {
            unsigned int v = (tid >= off) ? A[tid - off] : 0;
            __syncthreads();
            A[tid] += v;
            __syncthreads();
        }
        bccount[tid * 256 + bid] = A[tid] - c;   // exclusive over blocks
        if (tid == 255) totals[bid] = A[255];
    }
    grid.sync();

    // ---- P2: redundant scan of totals -> cbase (persisted by block 0) ----
    {
        unsigned int c = totals[tid];
        Bb[tid] = c;
        __syncthreads();
        for (int off = 1; off < 256; off <<= 1) {
            unsigned int v = (tid >= off) ? Bb[tid - off] : 0;
            __syncthreads();
            Bb[tid] += v;
            __syncthreads();
        }
        if (bid == 0) {
            cbase[tid] = Bb[tid] - c;
            if (tid == 255) cbase[256] = Bb[255];
        }
        A[tid] = (Bb[tid] - c) + bccount[bid * 256 + tid];  // scatter cursor
    }
    __syncthreads();

    // ---- P3: coarse scatter ----
    for (int e = e0 + tid; e < e0 + 8192; e += 256) {
        int s = ei[e];
        int d = ei[NEDGES_ + e];
        int bk = s >> 10;
        unsigned int pos = atomicAdd(&A[bk], 1u);
        rbuf[pos] = (((unsigned int)s & 1023u) << 7) | ((unsigned int)d & 127u);
    }
}

// ---------------------------------------------------------------------------
// K1 (MFMA): h = x @ W1 bf16, as_[n]=h.att_src, ad_[n]=h.att_dst.
// x tile [64][151] contiguous -> coalesced float4 stage, converted to bf16
// in-flight into Xs [64][160] (20480 B). Bs [64][160] (20480 B). Total LDS
// 40960 B = exactly 4 blocks/CU. Inner loop pure ds_read_b128 + MFMA.
// (verbatim from R7 — verified pass)
// ---------------------------------------------------------------------------
__global__ void __launch_bounds__(256) k1_mfma(
        const float* __restrict__ x, const bf16* __restrict__ Bt,
        const float* __restrict__ att_src, const float* __restrict__ att_dst,
        bf16* __restrict__ h, float* __restrict__ as_, float* __restrict__ ad_) {
    __shared__ __align__(16) bf16 Xs[64 * 160];
    __shared__ __align__(16) bf16 Bs[64 * 160];
    const int tid = threadIdx.x;
    const int rowbase = blockIdx.x * 64;

    {   // Bs copy: 1280 uint4, coalesced, L2/L3-resident
        const uint4* bsrc = (const uint4*)Bt;
        uint4* bdst = (uint4*)Bs;
        for (int i = tid; i < 1280; i += 256) bdst[i] = bsrc[i];
    }
    // Xs zero-pad cols 151..159 (64 rows x 9)
    for (int i = tid; i < 576; i += 256) {
        int r = i / 9, c = 151 + (i - (i / 9) * 9);
        Xs[r * 160 + c] = __float2bfloat16(0.f);
    }
    {   // Xs stage: 2416 float4 coalesced (38,656 B contiguous), cvt to bf16
        const float4* xsrc = (const float4*)(x + (size_t)rowbase * 151);
        for (int i = tid; i < 2416; i += 256) {
            float4 v = xsrc[i];
            unsigned gi = 4u * (unsigned)i;
            unsigned r = gi / 151u;
            unsigned c = gi - r * 151u;
            float vv[4] = {v.x, v.y, v.z, v.w};
#pragma unroll
            for (int j = 0; j < 4; j++) {
                Xs[r * 160 + c] = __float2bfloat16(vv[j]);
                if (++c == 151u) { c = 0u; ++r; }
            }
        }
    }
    __syncthreads();

    const int wv = tid >> 6, lane = tid & 63;
    const int quad = lane >> 4, m = lane & 15;
    const int arow = wv * 16 + m;

    f32x4 acc[4];
#pragma unroll
    for (int t = 0; t < 4; t++) acc[t] = (f32x4){0.f, 0.f, 0.f, 0.f};

#pragma unroll
    for (int ks = 0; ks < 5; ks++) {
        const int k0 = ks * 32 + quad * 8;
        bf16x8v af = *(const bf16x8v*)&Xs[arow * 160 + k0];
#pragma unroll
        for (int t = 0; t < 4; t++) {
            bf16x8v bfr = *(const bf16x8v*)&Bs[(t * 16 + m) * 160 + k0];
            acc[t] = __builtin_amdgcn_mfma_f32_16x16x32_bf16(af, bfr, acc[t], 0, 0, 0);
        }
    }

    float as4[4], ad4[4];
#pragma unroll
    for (int t = 0; t < 4; t++) {
        as4[t] = att_src[t * 16 + m];
        ad4[t] = att_dst[t * 16 + m];
    }
#pragma unroll
    for (int r = 0; r < 4; r++) {
        float s = acc[0][r] * as4[0] + acc[1][r] * as4[1] +
                  acc[2][r] * as4[2] + acc[3][r] * as4[3];
        float d = acc[0][r] * ad4[0] + acc[1][r] * ad4[1] +
                  acc[2][r] * ad4[2] + acc[3][r] * ad4[3];
#pragma unroll
        for (int off = 1; off <= 8; off <<= 1) {
            s += __shfl_xor(s, off);
            d += __shfl_xor(d, off);
        }
        const int node = rowbase + wv * 16 + quad * 4 + r;
        if (m == 0) { as_[node] = s; ad_[node] = d; }
#pragma unroll
        for (int t = 0; t < 4; t++) {
            float val = acc[t][r];
            float oth = __shfl_xor(val, 1);
            if (!(lane & 1)) {
                unsigned short lo = (unsigned short)f2bs(val);
                unsigned short hi = (unsigned short)f2bs(oth);
                unsigned int u = ((unsigned int)hi << 16) | lo;
                *(unsigned int*)&h[(size_t)node * 64 + t * 16 + m] = u;
            }
        }
    }
}

// ---------------------------------------------------------------------------
// K3: one graph per block, MFMA. Edges read straight from the coarse-sorted
// rbuf bucket (8 graphs, shared by 8 blocks -> L2-hot): pass p scans
// [cbase[g>>3], cbase[g>>3 + 1]) with one fused mask-compare selecting
// (graph, dst-quarter). No fine sort, no eb/base4. Row sums fused into the
// S->bf16 convert.
// LDS 52736 B static (3 blocks/CU):
//   Ab  bf16 [128][136]  @0       (34816)
//   S   fp32 [32][128]   @34816   (16384)  per-pass exp accumulator
//   hT  bf16 [64][136]   @34816   (17408)  staged after build (union with S)
//   dinv fp32[128]       @52224   (512)
// ---------------------------------------------------------------------------
__global__ void __launch_bounds__(256) k3_graph(
        const unsigned int* __restrict__ rbuf, const unsigned int* __restrict__ cbase,
        const bf16* __restrict__ h,
        const float* __restrict__ as_, const float* __restrict__ ad_,
        const float* __restrict__ b1, const float* __restrict__ Wlin,
        const float* __restrict__ blin, float* __restrict__ out) {
    __shared__ __align__(16) unsigned char lds[52736];
    short* Ab = (short*)lds;                               // [128][136]
    float* S = (float*)(lds + 34816);                      // [32][128]
    short* hT = (short*)(lds + 34816);                     // [64][136]
    float* dinv = (float*)(lds + 52224);                   // [128]

    const int tid = threadIdx.x;
    const int g = blockIdx.x;
    const float* asg = as_ + (g << 7);
    const float* adg = ad_ + (g << 7);
    const unsigned int* hgu = (const unsigned int*)(h + ((size_t)g << 13));

    const unsigned int cb0 = cbase[g >> 3];
    const unsigned int cb1 = cbase[(g >> 3) + 1];
    const unsigned int gtag = ((unsigned int)(g & 7)) << 14;

    // build A[dst][src] = exp(leakyrelu(alpha)) in 4 passes of 32 dst rows;
    // pass p filter-scans the coarse bucket. Self-loops injected in-pass.
#pragma unroll 1
    for (int p = 0; p < 4; p++) {
        for (int i = tid; i < 1024; i += 256)
            ((float4*)S)[i] = make_float4(0.f, 0.f, 0.f, 0.f);
        __syncthreads();
        if (tid < 32) {
            int node = 32 * p + tid;
            float a = asg[node] + adg[node];
            a = (a > 0.f) ? a : 0.2f * a;
            atomicAdd(&S[(tid << 7) + node], __expf(a));
        }
        const unsigned int sel = gtag | ((unsigned int)p << 5);
        for (unsigned int k = cb0 + tid; k < cb1; k += 256) {
            unsigned int rec = rbuf[k];
            if ((rec & 0x1C060u) == sel) {       // graph + dst-quarter match
                int sl = (rec >> 7) & 127, dl = rec & 127;
                float a = asg[sl] + adg[dl];
                a = (a > 0.f) ? a : 0.2f * a;
                atomicAdd(&S[((dl & 31) << 7) + sl], __expf(a));
            }
        }
        __syncthreads();
        // fused: convert S[32][128] -> Ab rows 32p.. (bf16, stride 136) AND
        // row sums. Thread covers 8 floats of a row; 16-lane shfl tree/row.
        float rs[2];
#pragma unroll
        for (int hf = 0; hf < 2; hf++) {
            int c = tid + (hf << 8);
            int r = c >> 4;
            int col = (c & 15) << 3;
            float4 v0 = ((const float4*)S)[c * 2];
            float4 v1 = ((const float4*)S)[c * 2 + 1];
            rs[hf] = v0.x + v0.y + v0.z + v0.w + v1.x + v1.y + v1.z + v1.w;
            bf16x8v pk = {f2bs(v0.x), f2bs(v0.y), f2bs(v0.z), f2bs(v0.w),
                          f2bs(v1.x), f2bs(v1.y), f2bs(v1.z), f2bs(v1.w)};
            *(bf16x8v*)&Ab[(32 * p + r) * 136 + col] = pk;
        }
#pragma unroll
        for (int off = 1; off <= 8; off <<= 1) {
            rs[0] += __shfl_xor(rs[0], off);
            rs[1] += __shfl_xor(rs[1], off);
        }
        if ((tid & 15) == 0) {
            dinv[32 * p + (tid >> 4)] = 1.f / rs[0];
            dinv[32 * p + 16 + (tid >> 4)] = 1.f / rs[1];
        }
        __syncthreads();
    }

    // stage hT[f][j] (transposed, stride 136) from h[j][f]
    for (int idx = tid; idx < 4096; idx += 256) {
        unsigned int u = hgu[idx];
        int j = idx >> 5, f2 = idx & 31;
        hT[(2 * f2) * 136 + j] = (short)(u & 0xFFFF);
        hT[(2 * f2 + 1) * 136 + j] = (short)(u >> 16);
    }
    __syncthreads();

    // MFMA: wave w -> rows i0=w*32 (2 M-tiles), 4 N-tiles, K=128 (4 steps)
    const int w = tid >> 6, lane = tid & 63;
    const int quad = lane >> 4, m = lane & 15;
    const int i0 = w * 32;
    f32x4 acc[2][4];
#pragma unroll
    for (int mt = 0; mt < 2; mt++)
#pragma unroll
        for (int nt = 0; nt < 4; nt++) acc[mt][nt] = (f32x4){0.f, 0.f, 0.f, 0.f};

#pragma unroll
    for (int ks = 0; ks < 4; ks++) {
        const int k0 = ks * 32 + quad * 8;
        bf16x8v a0 = *(const bf16x8v*)&Ab[(i0 + m) * 136 + k0];
        bf16x8v a1 = *(const bf16x8v*)&Ab[(i0 + 16 + m) * 136 + k0];
#pragma unroll
        for (int nt = 0; nt < 4; nt++) {
            bf16x8v bfr = *(const bf16x8v*)&hT[(nt * 16 + m) * 136 + k0];
            acc[0][nt] = __builtin_amdgcn_mfma_f32_16x16x32_bf16(a0, bfr, acc[0][nt], 0, 0, 0);
            acc[1][nt] = __builtin_amdgcn_mfma_f32_16x16x32_bf16(a1, bfr, acc[1][nt], 0, 0, 0);
        }
    }

    // epilogue: relu(acc*dinv + b1) . Wlin
    float dv[2][4];
#pragma unroll
    for (int mt = 0; mt < 2; mt++)
#pragma unroll
        for (int r = 0; r < 4; r++)
            dv[mt][r] = dinv[i0 + mt * 16 + quad * 4 + r];

    float p = 0.f;
#pragma unroll
    for (int nt = 0; nt < 4; nt++) {
        float bb = b1[nt * 16 + m];
#pragma unroll
        for (int mt = 0; mt < 2; mt++) {
#pragma unroll
            for (int r = 0; r < 4; r++) {
                int il = i0 + mt * 16 + quad * 4 + r;
                float v = acc[mt][nt][r] * dv[mt][r] + bb;
                v = v > 0.f ? v : 0.f;
                p += v * Wlin[il * 64 + nt * 16 + m];
            }
        }
    }
#pragma unroll
    for (int off = 32; off; off >>= 1) p += __shfl_xor(p, off);

    __syncthreads();
    if (lane == 0) S[w] = p;
    __syncthreads();
    if (tid == 0) {
        float logit = S[0] + S[1] + S[2] + S[3] + blin[0];
        out[g] = 1.f / (1.f + __expf(-logit));
    }
}

// ---------------------------------------------------------------------------
extern "C" void kernel_launch(void* const* d_in, const int* in_sizes, int n_in,
                              void* d_out, int out_size, void* d_ws, size_t ws_size,
                              hipStream_t stream) {
    (void)in_sizes; (void)n_in; (void)out_size; (void)ws_size;
    const float* x       = (const float*)d_in[0];
    const int*   ei      = (const int*)d_in[1];
    const float* W1      = (const float*)d_in[2];
    const float* att_src = (const float*)d_in[3];
    const float* att_dst = (const float*)d_in[4];
    const float* b1      = (const float*)d_in[5];
    const float* Wlin    = (const float*)d_in[6];
    const float* blin    = (const float*)d_in[7];
    float* out = (float*)d_out;

    char* ws = (char*)d_ws;
    bf16*           h       = (bf16*)ws;                        // 33,554,432 B
    float*          as_     = (float*)(ws + 33554432);          // 1 MB
    float*          ad_     = (float*)(ws + 34603008);          // 1 MB
    bf16*           Bt      = (bf16*)(ws + 35651584);           // 20,480 (pad 64K)
    unsigned int*   bccount = (unsigned int*)(ws + 35717120);   // 256*256*4 = 256 KB
    unsigned int*   cbase   = (unsigned int*)(ws + 35979264);   // 1,028 (pad 4K)
    unsigned int*   totals  = (unsigned int*)(ws + 35983360);   // 1,024 (pad 4K)
    unsigned int*   rbuf    = (unsigned int*)(ws + 35987456);   // 8,388,608

    void* sortArgs[] = {(void*)&ei, (void*)&W1, (void*)&Bt, (void*)&bccount,
                        (void*)&totals, (void*)&cbase, (void*)&rbuf};
    hipLaunchCooperativeKernel((const void*)kSort, dim3(256), dim3(256),
                               sortArgs, 0, stream);
    k1_mfma<<<NNODES_ / 64, 256, 0, stream>>>(x, Bt, att_src, att_dst, h, as_, ad_);
    k3_graph<<<G_, 256, 0, stream>>>(rbuf, cbase, h, as_, ad_, b1, Wlin, blin, out);
}

// Round 9
// 381.229 us; speedup vs baseline: 1.3943x; 1.3943x over previous
//
#include <hip/hip_runtime.h>
#include <hip/hip_bf16.h>

#define G_ 2048
#define NPG_ 128
#define INC_ 151
#define HID_ 64
#define NNODES_ (G_ * NPG_)      // 262144
#define NEDGES_ 2097152

typedef __hip_bfloat16 bf16;
typedef short bf16x8v __attribute__((ext_vector_type(8)));
typedef float f32x4 __attribute__((ext_vector_type(4)));

static __device__ __forceinline__ short f2bs(float f) {
    __hip_bfloat16 b = __float2bfloat16(f);
    return __builtin_bit_cast(short, b);
}

// ---------------------------------------------------------------------------
// k0C1 (fused): blocks 0..255 = coarse histogram (bucket = s>>10) into
// bccount[b][256]; blocks 256..297 = W1 [151][64] fp32 -> Bt [64][168] bf16
// (k >= 151 zero-padded).
// ---------------------------------------------------------------------------
__global__ void __launch_bounds__(256) k0C1(const float* __restrict__ W1,
                                            bf16* __restrict__ Bt,
                                            const int* __restrict__ ei,
                                            unsigned int* __restrict__ bccount) {
    __shared__ unsigned int hist[256];
    const int tid = threadIdx.x;
    if (blockIdx.x >= 256) {
        int i = (blockIdx.x - 256) * 256 + tid;
        if (i < 64 * 168) {
            int n = i / 168, k = i - n * 168;
            float v = (k < 151) ? W1[k * 64 + n] : 0.f;
            Bt[i] = __float2bfloat16(v);
        }
        return;
    }
    hist[tid] = 0;
    __syncthreads();
    const int e0 = blockIdx.x * 8192;
    for (int e = e0 + tid; e < e0 + 8192; e += 256)
        atomicAdd(&hist[ei[e] >> 10], 1u);
    __syncthreads();
    bccount[blockIdx.x * 256 + tid] = hist[tid];
}

// ---------------------------------------------------------------------------
// kC2a: 256 blocks, one bucket column each. Exclusive scan of bccount[*][bk]
// over the 256 coarse blocks (in place); bucket total -> totals[bk].
// ---------------------------------------------------------------------------
__global__ void __launch_bounds__(256) kC2a(unsigned int* __restrict__ bccount,
                                            unsigned int* __restrict__ totals) {
    __shared__ unsigned int sc[256];
    const int tid = threadIdx.x, bk = blockIdx.x;
    unsigned int c = bccount[tid * 256 + bk];
    sc[tid] = c;
    __syncthreads();
    for (int off = 1; off < 256; off <<= 1) {
        unsigned int v = (tid >= off) ? sc[tid - off] : 0;
        __syncthreads();
        sc[tid] += v;
        __syncthreads();
    }
    bccount[tid * 256 + bk] = sc[tid] - c;   // exclusive over blocks
    if (tid == 255) totals[bk] = sc[255];
}

// ---------------------------------------------------------------------------
// kC2b: 1 tiny block. Exclusive scan of 256 bucket totals -> cbase;
// sentinels cbase[256]=E, base8[G_*8]=E.
// ---------------------------------------------------------------------------
__global__ void __launch_bounds__(256) kC2b(const unsigned int* __restrict__ totals,
                                            unsigned int* __restrict__ cbase,
                                            unsigned int* __restrict__ base8) {
    __shared__ unsigned int sc[256];
    const int tid = threadIdx.x;
    unsigned int c = totals[tid];
    sc[tid] = c;
    __syncthreads();
    for (int off = 1; off < 256; off <<= 1) {
        unsigned int v = (tid >= off) ? sc[tid - off] : 0;
        __syncthreads();
        sc[tid] += v;
        __syncthreads();
    }
    cbase[tid] = sc[tid] - c;
    if (tid == 255) {
        cbase[256] = sc[255];
        base8[G_ * 8] = NEDGES_;
    }
}

// ---------------------------------------------------------------------------
// kC3: scatter u32 records ((s&1023)<<7 | dl) to coarse buckets.
// rec bits: [16:14]=g&7, [13:7]=sl, [6:0]=dl.
// ---------------------------------------------------------------------------
__global__ void __launch_bounds__(256) kC3_scatter(const int* __restrict__ ei,
                                                   const unsigned int* __restrict__ bccount,
                                                   const unsigned int* __restrict__ cbase,
                                                   unsigned int* __restrict__ rbuf) {
    __shared__ unsigned int cur[256];
    const int tid = threadIdx.x;
    cur[tid] = cbase[tid] + bccount[blockIdx.x * 256 + tid];
    __syncthreads();
    const int e0 = blockIdx.x * 8192;
    for (int e = e0 + tid; e < e0 + 8192; e += 256) {
        int s = ei[e];
        int d = ei[NEDGES_ + e];
        int bk = s >> 10;
        unsigned int pos = atomicAdd(&cur[bk], 1u);
        rbuf[pos] = (((unsigned int)s & 1023u) << 7) | ((unsigned int)d & 127u);
    }
}

// ---------------------------------------------------------------------------
// kC4: per coarse bucket (8 graphs): 64 fine buckets = (g&7)*8 + (dl>>4).
// Counts -> base8[8g+p]; final eb u16 ((sl<<7)|dl) written in per-(graph,
// dst-eighth) contiguous runs. 6-bit ballot-aggregated LDS cursors.
// ---------------------------------------------------------------------------
__global__ void __launch_bounds__(256) kC4_fine(const unsigned int* __restrict__ rbuf,
                                                const unsigned int* __restrict__ cbase,
                                                unsigned int* __restrict__ base8,
                                                unsigned short* __restrict__ eb) {
    __shared__ unsigned int lcnt[64];
    __shared__ unsigned int cur[64];
    const int tid = threadIdx.x;
    const int b = blockIdx.x;
    const unsigned int s0 = cbase[b], s1 = cbase[b + 1];
    if (tid < 64) lcnt[tid] = 0;
    __syncthreads();
    for (unsigned int i = s0 + tid; i < s1; i += 256) {
        unsigned int rec = rbuf[i];
        int key = ((rec >> 11) & 0x38) | ((rec >> 4) & 7);  // (g&7)*8 + eighth
        atomicAdd(&lcnt[key], 1u);
    }
    __syncthreads();
    if (tid == 0) {
        unsigned int r = 0;
#pragma unroll
        for (int j = 0; j < 64; j++) {
            base8[b * 64 + j] = s0 + r;
            cur[j] = s0 + r;
            r += lcnt[j];
        }
    }
    __syncthreads();
    const int lane = tid & 63;
    for (unsigned int i = s0 + tid; i < s1; i += 256) {
        unsigned int rec = rbuf[i];
        int key = ((rec >> 11) & 0x38) | ((rec >> 4) & 7);
        unsigned long long m = __ballot(1);
#pragma unroll
        for (int bit = 0; bit < 6; bit++) {
            unsigned long long bb = __ballot((key >> bit) & 1);
            m &= ((key >> bit) & 1) ? bb : ~bb;
        }
        int leader = __builtin_ctzll(m);
        int rank = __builtin_popcountll(m & ((1ull << lane) - 1ull));
        unsigned int bp = 0;
        if (lane == leader)
            bp = atomicAdd(&cur[key], (unsigned int)__builtin_popcountll(m));
        bp = __shfl((int)bp, leader);
        eb[bp + rank] = (unsigned short)(rec & 0x3FFFu);
    }
}

// ---------------------------------------------------------------------------
// K3 (fused GEMM + attention): one graph per block.
// Phase G: h = x[g*128..+128] @ W1 via MFMA, two 64-row halves staged in LDS
//   (Xs bf16 [64][168]); h written DIRECTLY into hT [feat][node] layout via
//   register-pair ds_write_b32; as/ad kept in LDS. No h/as/ad in HBM.
// Phase A: 8 passes of 16 dst rows; pass p streams its pre-sorted eb range
//   (base8). Row sums fused into S->bf16 convert. Final MFMA A=Ab, B=hT.
// LDS 61952 B (2 blocks/CU):
//   GEMM phase:  Bs [64][168] @0 (21504) | Xs [64][168] @21504 (21504)
//   attn  phase: Ab [128][136] @0 (34816) | S [16][128] @34816 (8192)
//   persistent:  hT [64][136] @43008 (17408) | asL @60416 | adL @60928
//                | dinv @61440 (512 each)
// ---------------------------------------------------------------------------
__global__ void __launch_bounds__(256) k3_graph(
        const float* __restrict__ x, const bf16* __restrict__ Bt,
        const float* __restrict__ att_src, const float* __restrict__ att_dst,
        const unsigned short* __restrict__ eb, const unsigned int* __restrict__ base8,
        const float* __restrict__ b1, const float* __restrict__ Wlin,
        const float* __restrict__ blin, float* __restrict__ out) {
    __shared__ __align__(16) unsigned char lds[61952];
    short* Bs = (short*)lds;                               // [64][168] (GEMM)
    short* Xs = (short*)(lds + 21504);                     // [64][168] (GEMM)
    short* Ab = (short*)lds;                               // [128][136] (attn)
    float* S = (float*)(lds + 34816);                      // [16][128] (attn)
    short* hT = (short*)(lds + 43008);                     // [64][136]
    float* asL = (float*)(lds + 60416);                    // [128]
    float* adL = (float*)(lds + 60928);                    // [128]
    float* dinv = (float*)(lds + 61440);                   // [128]

    const int tid = threadIdx.x;
    const int g = blockIdx.x;
    const int w = tid >> 6, lane = tid & 63;
    const int quad = lane >> 4, m = lane & 15;

    // ---- Phase G: per-graph GEMM h = x @ W1 ----
    {   // Bs: 1344 uint4, coalesced, L2/L3-hot
        const uint4* bsrc = (const uint4*)Bt;
        uint4* bdst = (uint4*)Bs;
        for (int i = tid; i < 1344; i += 256) bdst[i] = bsrc[i];
    }
    float as4[4], ad4[4];
#pragma unroll
    for (int t = 0; t < 4; t++) {
        as4[t] = att_src[t * 16 + m];
        ad4[t] = att_dst[t * 16 + m];
    }

#pragma unroll 1
    for (int half = 0; half < 2; half++) {
        // zero-pad Xs cols 151..159 (cols >=160 never read)
        for (int i = tid; i < 576; i += 256) {
            int r = i / 9, c = 151 + (i - (i / 9) * 9);
            Xs[r * 168 + c] = 0;
        }
        // stage 64 rows of x (38,656 B contiguous), cvt fp32->bf16 in flight
        const float4* xsrc = (const float4*)(x + ((size_t)g * 128 + half * 64) * 151);
        for (int i = tid; i < 2416; i += 256) {
            float4 v = xsrc[i];
            unsigned gi = 4u * (unsigned)i;
            unsigned r = gi / 151u;
            unsigned c = gi - r * 151u;
            float vv[4] = {v.x, v.y, v.z, v.w};
#pragma unroll
            for (int j = 0; j < 4; j++) {
                Xs[r * 168 + c] = f2bs(vv[j]);
                if (++c == 151u) { c = 0u; ++r; }
            }
        }
        __syncthreads();

        f32x4 acc[4];
#pragma unroll
        for (int t = 0; t < 4; t++) acc[t] = (f32x4){0.f, 0.f, 0.f, 0.f};
        const int xrow = w * 16 + m;
#pragma unroll
        for (int ks = 0; ks < 5; ks++) {
            const int k0 = ks * 32 + quad * 8;
            bf16x8v af = *(const bf16x8v*)&Xs[xrow * 168 + k0];
#pragma unroll
            for (int t = 0; t < 4; t++) {
                bf16x8v bfr = *(const bf16x8v*)&Bs[(t * 16 + m) * 168 + k0];
                acc[t] = __builtin_amdgcn_mfma_f32_16x16x32_bf16(af, bfr, acc[t], 0, 0, 0);
            }
        }
        // as/ad for the 4 nodes this thread's acc rows cover
        const int node0 = half * 64 + w * 16 + quad * 4;
#pragma unroll
        for (int r = 0; r < 4; r++) {
            float s = acc[0][r] * as4[0] + acc[1][r] * as4[1] +
                      acc[2][r] * as4[2] + acc[3][r] * as4[3];
            float d = acc[0][r] * ad4[0] + acc[1][r] * ad4[1] +
                      acc[2][r] * ad4[2] + acc[3][r] * ad4[3];
#pragma unroll
            for (int off = 1; off <= 8; off <<= 1) {
                s += __shfl_xor(s, off);
                d += __shfl_xor(d, off);
            }
            if (m == 0) { asL[node0 + r] = s; adL[node0 + r] = d; }
        }
        // h -> hT[feat][node] directly (register pairs, 2-way-free banks)
#pragma unroll
        for (int t = 0; t < 4; t++) {
            const int col = t * 16 + m;
            unsigned int u01 = ((unsigned int)(unsigned short)f2bs(acc[t][1]) << 16) |
                               (unsigned short)f2bs(acc[t][0]);
            unsigned int u23 = ((unsigned int)(unsigned short)f2bs(acc[t][3]) << 16) |
                               (unsigned short)f2bs(acc[t][2]);
            *(unsigned int*)&hT[col * 136 + node0] = u01;
            *(unsigned int*)&hT[col * 136 + node0 + 2] = u23;
        }
        __syncthreads();   // Xs/Bs reads done before next-half restage / Ab
    }

    // ---- Phase A: attention. 8 passes of 16 dst rows ----
#pragma unroll 1
    for (int p = 0; p < 8; p++) {
        for (int i = tid; i < 512; i += 256)
            ((float4*)S)[i] = make_float4(0.f, 0.f, 0.f, 0.f);
        __syncthreads();
        if (tid < 16) {
            int node = 16 * p + tid;
            float a = asL[node] + adL[node];
            a = (a > 0.f) ? a : 0.2f * a;
            atomicAdd(&S[(tid << 7) + node], __expf(a));
        }
        const unsigned int q0 = base8[(g << 3) + p];
        const unsigned int q1 = base8[(g << 3) + p + 1];
        for (unsigned int k = q0 + tid; k < q1; k += 256) {
            unsigned int v = eb[k];
            int sl = v >> 7, dl = v & 127;
            float a = asL[sl] + adL[dl];
            a = (a > 0.f) ? a : 0.2f * a;
            atomicAdd(&S[((dl & 15) << 7) + sl], __expf(a));
        }
        __syncthreads();
        // convert S[16][128] -> Ab rows 16p.. (bf16, stride 136) + row sums
        {
            int r = tid >> 4;
            int col = (tid & 15) << 3;
            float4 v0 = ((const float4*)S)[tid * 2];
            float4 v1 = ((const float4*)S)[tid * 2 + 1];
            float rs = v0.x + v0.y + v0.z + v0.w + v1.x + v1.y + v1.z + v1.w;
            bf16x8v pk = {f2bs(v0.x), f2bs(v0.y), f2bs(v0.z), f2bs(v0.w),
                          f2bs(v1.x), f2bs(v1.y), f2bs(v1.z), f2bs(v1.w)};
            *(bf16x8v*)&Ab[(16 * p + r) * 136 + col] = pk;
#pragma unroll
            for (int off = 1; off <= 8; off <<= 1) rs += __shfl_xor(rs, off);
            if ((tid & 15) == 0) dinv[16 * p + r] = 1.f / rs;
        }
        __syncthreads();
    }

    // ---- Final MFMA: wave w -> rows i0=w*32 (2 M-tiles), 4 N-tiles, K=128 ----
    const int i0 = w * 32;
    f32x4 acc[2][4];
#pragma unroll
    for (int mt = 0; mt < 2; mt++)
#pragma unroll
        for (int nt = 0; nt < 4; nt++) acc[mt][nt] = (f32x4){0.f, 0.f, 0.f, 0.f};

#pragma unroll
    for (int ks = 0; ks < 4; ks++) {
        const int k0 = ks * 32 + quad * 8;
        bf16x8v a0 = *(const bf16x8v*)&Ab[(i0 + m) * 136 + k0];
        bf16x8v a1 = *(const bf16x8v*)&Ab[(i0 + 16 + m) * 136 + k0];
#pragma unroll
        for (int nt = 0; nt < 4; nt++) {
            bf16x8v bfr = *(const bf16x8v*)&hT[(nt * 16 + m) * 136 + k0];
            acc[0][nt] = __builtin_amdgcn_mfma_f32_16x16x32_bf16(a0, bfr, acc[0][nt], 0, 0, 0);
            acc[1][nt] = __builtin_amdgcn_mfma_f32_16x16x32_bf16(a1, bfr, acc[1][nt], 0, 0, 0);
        }
    }

    // epilogue: relu(acc*dinv + b1) . Wlin
    float dv[2][4];
#pragma unroll
    for (int mt = 0; mt < 2; mt++)
#pragma unroll
        for (int r = 0; r < 4; r++)
            dv[mt][r] = dinv[i0 + mt * 16 + quad * 4 + r];

    float pacc = 0.f;
#pragma unroll
    for (int nt = 0; nt < 4; nt++) {
        float bb = b1[nt * 16 + m];
#pragma unroll
        for (int mt = 0; mt < 2; mt++) {
#pragma unroll
            for (int r = 0; r < 4; r++) {
                int il = i0 + mt * 16 + quad * 4 + r;
                float v = acc[mt][nt][r] * dv[mt][r] + bb;
                v = v > 0.f ? v : 0.f;
                pacc += v * Wlin[il * 64 + nt * 16 + m];
            }
        }
    }
#pragma unroll
    for (int off = 32; off; off >>= 1) pacc += __shfl_xor(pacc, off);

    __syncthreads();
    if (lane == 0) S[w] = pacc;
    __syncthreads();
    if (tid == 0) {
        float logit = S[0] + S[1] + S[2] + S[3] + blin[0];
        out[g] = 1.f / (1.f + __expf(-logit));
    }
}

// ---------------------------------------------------------------------------
extern "C" void kernel_launch(void* const* d_in, const int* in_sizes, int n_in,
                              void* d_out, int out_size, void* d_ws, size_t ws_size,
                              hipStream_t stream) {
    (void)in_sizes; (void)n_in; (void)out_size; (void)ws_size;
    const float* x       = (const float*)d_in[0];
    const int*   ei      = (const int*)d_in[1];
    const float* W1      = (const float*)d_in[2];
    const float* att_src = (const float*)d_in[3];
    const float* att_dst = (const float*)d_in[4];
    const float* b1      = (const float*)d_in[5];
    const float* Wlin    = (const float*)d_in[6];
    const float* blin    = (const float*)d_in[7];
    float* out = (float*)d_out;

    char* ws = (char*)d_ws;
    bf16*           Bt      = (bf16*)ws;                        // 21,504 (pad 64K)
    unsigned int*   bccount = (unsigned int*)(ws + 65536);      // 256 KB
    unsigned int*   cbase   = (unsigned int*)(ws + 327680);     // 1,028 (pad 4K)
    unsigned int*   totals  = (unsigned int*)(ws + 331776);     // 1,024 (pad 4K)
    unsigned int*   base8   = (unsigned int*)(ws + 335872);     // 65,540 (pad 68K)
    unsigned int*   rbuf    = (unsigned int*)(ws + 405504);     // 8,388,608
    unsigned short* eb      = (unsigned short*)(ws + 8794112);  // 4,194,304

    k0C1<<<298, 256, 0, stream>>>(W1, Bt, ei, bccount);
    kC2a<<<256, 256, 0, stream>>>(bccount, totals);
    kC2b<<<1, 256, 0, stream>>>(totals, cbase, base8);
    kC3_scatter<<<256, 256, 0, stream>>>(ei, bccount, cbase, rbuf);
    kC4_fine<<<256, 256, 0, stream>>>(rbuf, cbase, base8, eb);
    k3_graph<<<G_, 256, 0, stream>>>(x, Bt, att_src, att_dst, eb, base8,
                                     b1, Wlin, blin, out);
}

// Round 10
// 366.163 us; speedup vs baseline: 1.4517x; 1.0411x over previous
//
#include <hip/hip_runtime.h>
#include <hip/hip_bf16.h>

#define G_ 2048
#define NPG_ 128
#define INC_ 151
#define HID_ 64
#define NNODES_ (G_ * NPG_)      // 262144
#define NEDGES_ 2097152

typedef __hip_bfloat16 bf16;
typedef short bf16x8v __attribute__((ext_vector_type(8)));
typedef float f32x4 __attribute__((ext_vector_type(4)));

static __device__ __forceinline__ short f2bs(float f) {
    __hip_bfloat16 b = __float2bfloat16(f);
    return __builtin_bit_cast(short, b);
}

// ---------------------------------------------------------------------------
// k0C1 (fused): blocks 0..255 = coarse histogram (bucket = s>>10) into
// bccount[b][256] (RAW counts, scans recomputed downstream);
// blocks 256..295 = W1 [151][64] fp32 -> Bt [64][160] bf16 (zero-padded).
// ---------------------------------------------------------------------------
__global__ void __launch_bounds__(256) k0C1(const float* __restrict__ W1,
                                            bf16* __restrict__ Bt,
                                            const int* __restrict__ ei,
                                            unsigned int* __restrict__ bccount) {
    __shared__ unsigned int hist[256];
    const int tid = threadIdx.x;
    if (blockIdx.x >= 256) {
        int i = (blockIdx.x - 256) * 256 + tid;   // 40*256 == 64*160 exactly
        int n = i / 160, k = i - n * 160;
        float v = (k < 151) ? W1[k * 64 + n] : 0.f;
        Bt[i] = __float2bfloat16(v);
        return;
    }
    hist[tid] = 0;
    __syncthreads();
    const int e0 = blockIdx.x * 8192;
    for (int e = e0 + tid; e < e0 + 8192; e += 256)
        atomicAdd(&hist[ei[e] >> 10], 1u);
    __syncthreads();
    bccount[blockIdx.x * 256 + tid] = hist[tid];
}

// ---------------------------------------------------------------------------
// kC3: coarse scatter. Each block redundantly derives its cursors from the
// raw bccount (256 coalesced row-reads, L2-hot) + LDS scan of totals.
// rec bits: [16:14]=g&7, [13:7]=sl, [6:0]=dl.
// ---------------------------------------------------------------------------
__global__ void __launch_bounds__(256) kC3_scatter(const int* __restrict__ ei,
                                                   const unsigned int* __restrict__ bccount,
                                                   unsigned int* __restrict__ rbuf) {
    __shared__ unsigned int sc[256];
    __shared__ unsigned int cur[256];
    const int tid = threadIdx.x;
    const int j = blockIdx.x;
    unsigned int part = 0, tot = 0;
    for (int i = 0; i < 256; i++) {
        unsigned int c = bccount[i * 256 + tid];
        if (i < j) part += c;
        tot += c;
    }
    sc[tid] = tot;
    __syncthreads();
    for (int off = 1; off < 256; off <<= 1) {
        unsigned int v = (tid >= off) ? sc[tid - off] : 0;
        __syncthreads();
        sc[tid] += v;
        __syncthreads();
    }
    cur[tid] = (sc[tid] - tot) + part;     // cbase[tid] + excl-over-blocks
    __syncthreads();
    const int e0 = j * 8192;
    for (int e = e0 + tid; e < e0 + 8192; e += 256) {
        int s = ei[e];
        int d = ei[NEDGES_ + e];
        int bk = s >> 10;
        unsigned int pos = atomicAdd(&cur[bk], 1u);
        rbuf[pos] = (((unsigned int)s & 1023u) << 7) | ((unsigned int)d & 127u);
    }
}

// ---------------------------------------------------------------------------
// kC4: per coarse bucket (8 graphs): 64 fine buckets = (g&7)*8 + (dl>>4).
// Recomputes cbase from raw bccount. Counts -> base8[8g+p]; final eb u16
// ((sl<<7)|dl) in per-(graph, dst-eighth) runs. 6-bit ballot cursors.
// Block 255 writes the base8[G*8]=E sentinel.
// ---------------------------------------------------------------------------
__global__ void __launch_bounds__(256) kC4_fine(const unsigned int* __restrict__ rbuf,
                                                const unsigned int* __restrict__ bccount,
                                                unsigned int* __restrict__ base8,
                                                unsigned short* __restrict__ eb) {
    __shared__ unsigned int sc[256];
    __shared__ unsigned int lcnt[64];
    __shared__ unsigned int cur[64];
    const int tid = threadIdx.x;
    const int b = blockIdx.x;
    unsigned int tot = 0;
    for (int i = 0; i < 256; i++) tot += bccount[i * 256 + tid];
    sc[tid] = tot;
    if (tid < 64) lcnt[tid] = 0;
    __syncthreads();
    for (int off = 1; off < 256; off <<= 1) {
        unsigned int v = (tid >= off) ? sc[tid - off] : 0;
        __syncthreads();
        sc[tid] += v;
        __syncthreads();
    }
    const unsigned int s0 = (b > 0) ? sc[b - 1] : 0;
    const unsigned int s1 = sc[b];
    for (unsigned int i = s0 + tid; i < s1; i += 256) {
        unsigned int rec = rbuf[i];
        int key = ((rec >> 11) & 0x38) | ((rec >> 4) & 7);  // (g&7)*8 + eighth
        atomicAdd(&lcnt[key], 1u);
    }
    __syncthreads();
    if (tid == 0) {
        unsigned int r = 0;
#pragma unroll
        for (int j = 0; j < 64; j++) {
            base8[b * 64 + j] = s0 + r;
            cur[j] = s0 + r;
            r += lcnt[j];
        }
        if (b == 255) base8[G_ * 8] = NEDGES_;
    }
    __syncthreads();
    const int lane = tid & 63;
    for (unsigned int i = s0 + tid; i < s1; i += 256) {
        unsigned int rec = rbuf[i];
        int key = ((rec >> 11) & 0x38) | ((rec >> 4) & 7);
        unsigned long long m = __ballot(1);
#pragma unroll
        for (int bit = 0; bit < 6; bit++) {
            unsigned long long bb = __ballot((key >> bit) & 1);
            m &= ((key >> bit) & 1) ? bb : ~bb;
        }
        int leader = __builtin_ctzll(m);
        int rank = __builtin_popcountll(m & ((1ull << lane) - 1ull));
        unsigned int bp = 0;
        if (lane == leader)
            bp = atomicAdd(&cur[key], (unsigned int)__builtin_popcountll(m));
        bp = __shfl((int)bp, leader);
        eb[bp + rank] = (unsigned short)(rec & 0x3FFFu);
    }
}

// ---------------------------------------------------------------------------
// K3 (fused GEMM + attention, 512 threads): one graph per block.
// Phase G: full 128-row x tile staged once (bf16, stride 160); 8 waves each
//   compute one 16-row M-tile (20 MFMAs); h written directly to hT
//   [feat][node]; as/ad to LDS. Phase A: 8 passes of 16 dst rows from the
//   pre-sorted eb (base8); row sums fused into S->bf16 convert. Final MFMA:
//   wave w = rows w*16..w*16+15, 4 N-tiles, K=128 (16 MFMAs).
// LDS 80384 B -> 2 blocks/CU x 8 waves = 16 waves/CU:
//   GEMM: Xs[128][160] @0 (40960) | Bs[64][160] @40960 (20480)
//   attn: Ab[128][136] @0 (34816) | S[16][128] @34816 (8192)
//   persistent: hT[64][136] @61440 (17408) | asL @78848 | adL @79360
//               | dinv @79872 (512 each)
// ---------------------------------------------------------------------------
__global__ void __launch_bounds__(512, 4) k3_graph(
        const float* __restrict__ x, const bf16* __restrict__ Bt,
        const float* __restrict__ att_src, const float* __restrict__ att_dst,
        const unsigned short* __restrict__ eb, const unsigned int* __restrict__ base8,
        const float* __restrict__ b1, const float* __restrict__ Wlin,
        const float* __restrict__ blin, float* __restrict__ out) {
    __shared__ __align__(16) unsigned char lds[80384];
    short* Xs = (short*)lds;                               // [128][160] (GEMM)
    short* Bs = (short*)(lds + 40960);                     // [64][160]  (GEMM)
    short* Ab = (short*)lds;                               // [128][136] (attn)
    float* S = (float*)(lds + 34816);                      // [16][128]  (attn)
    short* hT = (short*)(lds + 61440);                     // [64][136]
    float* asL = (float*)(lds + 78848);                    // [128]
    float* adL = (float*)(lds + 79360);                    // [128]
    float* dinv = (float*)(lds + 79872);                   // [128]

    const int tid = threadIdx.x;
    const int g = blockIdx.x;
    const int w = tid >> 6, lane = tid & 63;
    const int quad = lane >> 4, m = lane & 15;

    // ---- Phase G: per-graph GEMM h = x @ W1 ----
    {   // Bs: 1280 uint4, coalesced, L2/L3-hot
        const uint4* bsrc = (const uint4*)Bt;
        uint4* bdst = (uint4*)Bs;
        for (int i = tid; i < 1280; i += 512) bdst[i] = bsrc[i];
    }
    // Xs zero-pad cols 151..159 (128 rows x 9)
    for (int i = tid; i < 1152; i += 512) {
        int r = i / 9, c = 151 + (i - (i / 9) * 9);
        Xs[r * 160 + c] = 0;
    }
    {   // Xs stage: 4832 float4 coalesced (77,312 B contiguous), cvt to bf16
        const float4* xsrc = (const float4*)(x + (size_t)g * 128 * 151);
        for (int i = tid; i < 4832; i += 512) {
            float4 v = xsrc[i];
            unsigned gi = 4u * (unsigned)i;
            unsigned r = gi / 151u;
            unsigned c = gi - r * 151u;
            float vv[4] = {v.x, v.y, v.z, v.w};
#pragma unroll
            for (int j = 0; j < 4; j++) {
                Xs[r * 160 + c] = f2bs(vv[j]);
                if (++c == 151u) { c = 0u; ++r; }
            }
        }
    }
    float as4[4], ad4[4];
#pragma unroll
    for (int t = 0; t < 4; t++) {
        as4[t] = att_src[t * 16 + m];
        ad4[t] = att_dst[t * 16 + m];
    }
    __syncthreads();

    {
        f32x4 acc[4];
#pragma unroll
        for (int t = 0; t < 4; t++) acc[t] = (f32x4){0.f, 0.f, 0.f, 0.f};
        const int xrow = w * 16 + m;
#pragma unroll
        for (int ks = 0; ks < 5; ks++) {
            const int k0 = ks * 32 + quad * 8;
            bf16x8v af = *(const bf16x8v*)&Xs[xrow * 160 + k0];
#pragma unroll
            for (int t = 0; t < 4; t++) {
                bf16x8v bfr = *(const bf16x8v*)&Bs[(t * 16 + m) * 160 + k0];
                acc[t] = __builtin_amdgcn_mfma_f32_16x16x32_bf16(af, bfr, acc[t], 0, 0, 0);
            }
        }
        // as/ad for the 4 nodes this thread's acc rows cover
        const int node0 = w * 16 + quad * 4;
#pragma unroll
        for (int r = 0; r < 4; r++) {
            float s = acc[0][r] * as4[0] + acc[1][r] * as4[1] +
                      acc[2][r] * as4[2] + acc[3][r] * as4[3];
            float d = acc[0][r] * ad4[0] + acc[1][r] * ad4[1] +
                      acc[2][r] * ad4[2] + acc[3][r] * ad4[3];
#pragma unroll
            for (int off = 1; off <= 8; off <<= 1) {
                s += __shfl_xor(s, off);
                d += __shfl_xor(d, off);
            }
            if (m == 0) { asL[node0 + r] = s; adL[node0 + r] = d; }
        }
        // h -> hT[feat][node] directly (register pairs, 2-way-free banks)
#pragma unroll
        for (int t = 0; t < 4; t++) {
            const int col = t * 16 + m;
            unsigned int u01 = ((unsigned int)(unsigned short)f2bs(acc[t][1]) << 16) |
                               (unsigned short)f2bs(acc[t][0]);
            unsigned int u23 = ((unsigned int)(unsigned short)f2bs(acc[t][3]) << 16) |
                               (unsigned short)f2bs(acc[t][2]);
            *(unsigned int*)&hT[col * 136 + node0] = u01;
            *(unsigned int*)&hT[col * 136 + node0 + 2] = u23;
        }
    }
    __syncthreads();   // GEMM reads of Xs/Bs done before Ab/S overlay writes

    // ---- Phase A: attention. 8 passes of 16 dst rows ----
#pragma unroll 1
    for (int p = 0; p < 8; p++) {
        ((float4*)S)[tid] = make_float4(0.f, 0.f, 0.f, 0.f);  // 512 = exact
        __syncthreads();
        if (tid < 16) {
            int node = 16 * p + tid;
            float a = asL[node] + adL[node];
            a = (a > 0.f) ? a : 0.2f * a;
            atomicAdd(&S[(tid << 7) + node], __expf(a));
        }
        const unsigned int q0 = base8[(g << 3) + p];
        const unsigned int q1 = base8[(g << 3) + p + 1];
        for (unsigned int k = q0 + tid; k < q1; k += 512) {
            unsigned int v = eb[k];
            int sl = v >> 7, dl = v & 127;
            float a = asL[sl] + adL[dl];
            a = (a > 0.f) ? a : 0.2f * a;
            atomicAdd(&S[((dl & 15) << 7) + sl], __expf(a));
        }
        __syncthreads();
        // convert S[16][128] -> Ab rows 16p.. (bf16, stride 136) + row sums
        {
            int r = tid >> 5;
            int col = (tid & 31) << 2;
            float4 v = ((const float4*)S)[tid];
            float rs = v.x + v.y + v.z + v.w;
            unsigned int u01 = ((unsigned int)(unsigned short)f2bs(v.y) << 16) |
                               (unsigned short)f2bs(v.x);
            unsigned int u23 = ((unsigned int)(unsigned short)f2bs(v.w) << 16) |
                               (unsigned short)f2bs(v.z);
            uint2 pk = make_uint2(u01, u23);
            *(uint2*)&Ab[(16 * p + r) * 136 + col] = pk;
#pragma unroll
            for (int off = 1; off <= 16; off <<= 1) rs += __shfl_xor(rs, off);
            if ((tid & 31) == 0) dinv[16 * p + r] = 1.f / rs;
        }
        __syncthreads();
    }

    // ---- Final MFMA: wave w -> rows i0=w*16 (1 M-tile), 4 N-tiles, K=128 ----
    const int i0 = w * 16;
    f32x4 acc[4];
#pragma unroll
    for (int nt = 0; nt < 4; nt++) acc[nt] = (f32x4){0.f, 0.f, 0.f, 0.f};

#pragma unroll
    for (int ks = 0; ks < 4; ks++) {
        const int k0 = ks * 32 + quad * 8;
        bf16x8v a0 = *(const bf16x8v*)&Ab[(i0 + m) * 136 + k0];
#pragma unroll
        for (int nt = 0; nt < 4; nt++) {
            bf16x8v bfr = *(const bf16x8v*)&hT[(nt * 16 + m) * 136 + k0];
            acc[nt] = __builtin_amdgcn_mfma_f32_16x16x32_bf16(a0, bfr, acc[nt], 0, 0, 0);
        }
    }

    // epilogue: relu(acc*dinv + b1) . Wlin
    float dv[4];
#pragma unroll
    for (int r = 0; r < 4; r++) dv[r] = dinv[i0 + quad * 4 + r];

    float pacc = 0.f;
#pragma unroll
    for (int nt = 0; nt < 4; nt++) {
        float bb = b1[nt * 16 + m];
#pragma unroll
        for (int r = 0; r < 4; r++) {
            int il = i0 + quad * 4 + r;
            float v = acc[nt][r] * dv[r] + bb;
            v = v > 0.f ? v : 0.f;
            pacc += v * Wlin[il * 64 + nt * 16 + m];
        }
    }
#pragma unroll
    for (int off = 32; off; off >>= 1) pacc += __shfl_xor(pacc, off);

    __syncthreads();
    if (lane == 0) S[w] = pacc;
    __syncthreads();
    if (tid == 0) {
        float logit = S[0] + S[1] + S[2] + S[3] +
                      S[4] + S[5] + S[6] + S[7] + blin[0];
        out[g] = 1.f / (1.f + __expf(-logit));
    }
}

// ---------------------------------------------------------------------------
extern "C" void kernel_launch(void* const* d_in, const int* in_sizes, int n_in,
                              void* d_out, int out_size, void* d_ws, size_t ws_size,
                              hipStream_t stream) {
    (void)in_sizes; (void)n_in; (void)out_size; (void)ws_size;
    const float* x       = (const float*)d_in[0];
    const int*   ei      = (const int*)d_in[1];
    const float* W1      = (const float*)d_in[2];
    const float* att_src = (const float*)d_in[3];
    const float* att_dst = (const float*)d_in[4];
    const float* b1      = (const float*)d_in[5];
    const float* Wlin    = (const float*)d_in[6];
    const float* blin    = (const float*)d_in[7];
    float* out = (float*)d_out;

    char* ws = (char*)d_ws;
    bf16*           Bt      = (bf16*)ws;                        // 20,480 (pad 64K)
    unsigned int*   bccount = (unsigned int*)(ws + 65536);      // 256 KB
    unsigned int*   base8   = (unsigned int*)(ws + 327680);     // 65,540 (pad 68K)
    unsigned int*   rbuf    = (unsigned int*)(ws + 397312);     // 8,388,608
    unsigned short* eb      = (unsigned short*)(ws + 8785920);  // 4,194,304

    k0C1<<<296, 256, 0, stream>>>(W1, Bt, ei, bccount);
    kC3_scatter<<<256, 256, 0, stream>>>(ei, bccount, rbuf);
    kC4_fine<<<256, 256, 0, stream>>>(rbuf, bccount, base8, eb);
    k3_graph<<<G_, 512, 0, stream>>>(x, Bt, att_src, att_dst, eb, base8,
                                     b1, Wlin, blin, out);
}

// Round 11
// 351.752 us; speedup vs baseline: 1.5112x; 1.0410x over previous
//
#include <hip/hip_runtime.h>
#include <hip/hip_bf16.h>

#define G_ 2048
#define NPG_ 128
#define INC_ 151
#define HID_ 64
#define NNODES_ (G_ * NPG_)      // 262144
#define NEDGES_ 2097152

typedef __hip_bfloat16 bf16;
typedef short bf16x8v __attribute__((ext_vector_type(8)));
typedef float f32x4 __attribute__((ext_vector_type(4)));

static __device__ __forceinline__ short f2bs(float f) {
    __hip_bfloat16 b = __float2bfloat16(f);
    return __builtin_bit_cast(short, b);
}

// ---------------------------------------------------------------------------
// k0C1 (fused): blocks 0..255 = coarse histogram (bucket = s>>10) into
// bccount[b][256] (RAW counts, scans recomputed downstream);
// blocks 256..295 = W1 [151][64] fp32 -> Bt [64][160] bf16 (zero-padded).
// ---------------------------------------------------------------------------
__global__ void __launch_bounds__(256) k0C1(const float* __restrict__ W1,
                                            bf16* __restrict__ Bt,
                                            const int* __restrict__ ei,
                                            unsigned int* __restrict__ bccount) {
    __shared__ unsigned int hist[256];
    const int tid = threadIdx.x;
    if (blockIdx.x >= 256) {
        int i = (blockIdx.x - 256) * 256 + tid;   // 40*256 == 64*160 exactly
        int n = i / 160, k = i - n * 160;
        float v = (k < 151) ? W1[k * 64 + n] : 0.f;
        Bt[i] = __float2bfloat16(v);
        return;
    }
    hist[tid] = 0;
    __syncthreads();
    const int e0 = blockIdx.x * 8192;
    for (int e = e0 + tid; e < e0 + 8192; e += 256)
        atomicAdd(&hist[ei[e] >> 10], 1u);
    __syncthreads();
    bccount[blockIdx.x * 256 + tid] = hist[tid];
}

// ---------------------------------------------------------------------------
// kC3: coarse scatter. Each block redundantly derives its cursors from the
// raw bccount (256 coalesced row-reads, L2-hot) + LDS scan of totals.
// Block 0 persists cbase[0..256] for k3. rec bits: [16:14]=g&7, [13:7]=sl,
// [6:0]=dl.
// ---------------------------------------------------------------------------
__global__ void __launch_bounds__(256) kC3_scatter(const int* __restrict__ ei,
                                                   const unsigned int* __restrict__ bccount,
                                                   unsigned int* __restrict__ cbase,
                                                   unsigned int* __restrict__ rbuf) {
    __shared__ unsigned int sc[256];
    __shared__ unsigned int cur[256];
    const int tid = threadIdx.x;
    const int j = blockIdx.x;
    unsigned int part = 0, tot = 0;
    for (int i = 0; i < 256; i++) {
        unsigned int c = bccount[i * 256 + tid];
        if (i < j) part += c;
        tot += c;
    }
    sc[tid] = tot;
    __syncthreads();
    for (int off = 1; off < 256; off <<= 1) {
        unsigned int v = (tid >= off) ? sc[tid - off] : 0;
        __syncthreads();
        sc[tid] += v;
        __syncthreads();
    }
    cur[tid] = (sc[tid] - tot) + part;     // cbase[tid] + excl-over-blocks
    if (j == 0) {
        cbase[tid] = sc[tid] - tot;
        if (tid == 255) cbase[256] = sc[255];   // = NEDGES_
    }
    __syncthreads();
    const int e0 = j * 8192;
    for (int e = e0 + tid; e < e0 + 8192; e += 256) {
        int s = ei[e];
        int d = ei[NEDGES_ + e];
        int bk = s >> 10;
        unsigned int pos = atomicAdd(&cur[bk], 1u);
        rbuf[pos] = (((unsigned int)s & 1023u) << 7) | ((unsigned int)d & 127u);
    }
}

// ---------------------------------------------------------------------------
// K3 (fused GEMM + bin + attention, 512 threads): one graph per block.
// Phase G: full 128-row x tile staged once (bf16, stride 160); 8 waves each
//   compute one 16-row M-tile; h written directly to hT [feat][node]; as/ad
//   to LDS.
// Phase B: read this graph's 8-graph coarse rbuf slice once (L2-hot, shared
//   by 8 sibling blocks), keep own-graph records, bin by dst-quarter into
//   elist[4][512] u16 (+32-entry overflow list); zero S concurrently.
// Phase A: 4 passes of 32 dst rows from LDS lists; convert+rowsum+rezero
//   fused (2 barriers/pass). Final MFMA: wave w = rows w*16, 4 N-tiles,
//   K=128.
// LDS 80544 B -> 2 blocks/CU x 8 waves = 16 waves/CU:
//   GEMM: Xs[128][160] @0 (40960) | Bs[64][160] @40960 (20480)
//   attn: Ab[128][136] @0 (34816) | S[32][128] @34816 (16384)
//         | elist[4][512]u16 @51200 (4096) | (free to 61440)
//   persistent: hT[64][136] @61440 (17408) | asL @78848 | adL @79360
//               | dinv @79872 | cnt4 @80384 (16) | ovfn @80400 (4)
//               | ovfl[32] @80404..80532
// ---------------------------------------------------------------------------
__global__ void __launch_bounds__(512, 4) k3_graph(
        const float* __restrict__ x, const bf16* __restrict__ Bt,
        const float* __restrict__ att_src, const float* __restrict__ att_dst,
        const unsigned int* __restrict__ rbuf, const unsigned int* __restrict__ cbase,
        const float* __restrict__ b1, const float* __restrict__ Wlin,
        const float* __restrict__ blin, float* __restrict__ out) {
    __shared__ __align__(16) unsigned char lds[80544];
    short* Xs = (short*)lds;                               // [128][160] (GEMM)
    short* Bs = (short*)(lds + 40960);                     // [64][160]  (GEMM)
    short* Ab = (short*)lds;                               // [128][136] (attn)
    float* S = (float*)(lds + 34816);                      // [32][128]  (attn)
    unsigned short* elist = (unsigned short*)(lds + 51200);// [4][512]
    short* hT = (short*)(lds + 61440);                     // [64][136]
    float* asL = (float*)(lds + 78848);                    // [128]
    float* adL = (float*)(lds + 79360);                    // [128]
    float* dinv = (float*)(lds + 79872);                   // [128]
    unsigned int* cnt4 = (unsigned int*)(lds + 80384);     // [4]
    unsigned int* ovfn = (unsigned int*)(lds + 80400);     // [1]
    unsigned int* ovfl = (unsigned int*)(lds + 80404);     // [32]

    const int tid = threadIdx.x;
    const int g = blockIdx.x;
    const int w = tid >> 6, lane = tid & 63;
    const int quad = lane >> 4, m = lane & 15;

    // ---- Phase G: per-graph GEMM h = x @ W1 ----
    if (tid < 4) cnt4[tid] = 0;            // persistent region: safe pre-GEMM
    if (tid == 4) ovfn[0] = 0;
    {   // Bs: 1280 uint4, coalesced, L2/L3-hot
        const uint4* bsrc = (const uint4*)Bt;
        uint4* bdst = (uint4*)Bs;
        for (int i = tid; i < 1280; i += 512) bdst[i] = bsrc[i];
    }
    // Xs zero-pad cols 151..159 (128 rows x 9)
    for (int i = tid; i < 1152; i += 512) {
        int r = i / 9, c = 151 + (i - (i / 9) * 9);
        Xs[r * 160 + c] = 0;
    }
    {   // Xs stage: 4832 float4 coalesced (77,312 B contiguous), cvt to bf16
        const float4* xsrc = (const float4*)(x + (size_t)g * 128 * 151);
        for (int i = tid; i < 4832; i += 512) {
            float4 v = xsrc[i];
            unsigned gi = 4u * (unsigned)i;
            unsigned r = gi / 151u;
            unsigned c = gi - r * 151u;
            float vv[4] = {v.x, v.y, v.z, v.w};
#pragma unroll
            for (int j = 0; j < 4; j++) {
                Xs[r * 160 + c] = f2bs(vv[j]);
                if (++c == 151u) { c = 0u; ++r; }
            }
        }
    }
    float as4[4], ad4[4];
#pragma unroll
    for (int t = 0; t < 4; t++) {
        as4[t] = att_src[t * 16 + m];
        ad4[t] = att_dst[t * 16 + m];
    }
    __syncthreads();

    {
        f32x4 acc[4];
#pragma unroll
        for (int t = 0; t < 4; t++) acc[t] = (f32x4){0.f, 0.f, 0.f, 0.f};
        const int xrow = w * 16 + m;
#pragma unroll
        for (int ks = 0; ks < 5; ks++) {
            const int k0 = ks * 32 + quad * 8;
            bf16x8v af = *(const bf16x8v*)&Xs[xrow * 160 + k0];
#pragma unroll
            for (int t = 0; t < 4; t++) {
                bf16x8v bfr = *(const bf16x8v*)&Bs[(t * 16 + m) * 160 + k0];
                acc[t] = __builtin_amdgcn_mfma_f32_16x16x32_bf16(af, bfr, acc[t], 0, 0, 0);
            }
        }
        // as/ad for the 4 nodes this thread's acc rows cover
        const int node0 = w * 16 + quad * 4;
#pragma unroll
        for (int r = 0; r < 4; r++) {
            float s = acc[0][r] * as4[0] + acc[1][r] * as4[1] +
                      acc[2][r] * as4[2] + acc[3][r] * as4[3];
            float d = acc[0][r] * ad4[0] + acc[1][r] * ad4[1] +
                      acc[2][r] * ad4[2] + acc[3][r] * ad4[3];
#pragma unroll
            for (int off = 1; off <= 8; off <<= 1) {
                s += __shfl_xor(s, off);
                d += __shfl_xor(d, off);
            }
            if (m == 0) { asL[node0 + r] = s; adL[node0 + r] = d; }
        }
        // h -> hT[feat][node] directly (register pairs, 2-way-free banks)
#pragma unroll
        for (int t = 0; t < 4; t++) {
            const int col = t * 16 + m;
            unsigned int u01 = ((unsigned int)(unsigned short)f2bs(acc[t][1]) << 16) |
                               (unsigned short)f2bs(acc[t][0]);
            unsigned int u23 = ((unsigned int)(unsigned short)f2bs(acc[t][3]) << 16) |
                               (unsigned short)f2bs(acc[t][2]);
            *(unsigned int*)&hT[col * 136 + node0] = u01;
            *(unsigned int*)&hT[col * 136 + node0 + 2] = u23;
        }
    }
    __syncthreads();   // GEMM reads of Xs/Bs done; overlays may be written

    // ---- Phase B: bin own-graph edges by dst-quarter into LDS; zero S ----
    {
        for (int i = tid; i < 1024; i += 512)
            ((float4*)S)[i] = make_float4(0.f, 0.f, 0.f, 0.f);
        const unsigned int cb0 = cbase[g >> 3];
        const unsigned int cb1 = cbase[(g >> 3) + 1];
        const unsigned int gt = (unsigned int)(g & 7);
        for (unsigned int k = cb0 + tid; k < cb1; k += 512) {
            unsigned int rec = rbuf[k];
            if ((rec >> 14) == gt) {
                int q = (rec >> 5) & 3;
                unsigned int pos = atomicAdd(&cnt4[q], 1u);
                if (pos < 512u) {
                    elist[q * 512 + pos] = (unsigned short)(rec & 0x3FFFu);
                } else {
                    unsigned int oi = atomicAdd(ovfn, 1u);
                    if (oi < 32u) ovfl[oi] = rec & 0x3FFFu;
                }
            }
        }
    }
    __syncthreads();

    // ---- Phase A: 4 passes of 32 dst rows from LDS lists ----
    const unsigned int novf = ovfn[0] < 32u ? ovfn[0] : 32u;
#pragma unroll 1
    for (int p = 0; p < 4; p++) {
        if (tid < 32) {
            int node = 32 * p + tid;
            float a = asL[node] + adL[node];
            a = (a > 0.f) ? a : 0.2f * a;
            atomicAdd(&S[(tid << 7) + node], __expf(a));
        }
        unsigned int cnt = cnt4[p] < 512u ? cnt4[p] : 512u;
        for (unsigned int k = tid; k < cnt; k += 512) {
            unsigned int v = elist[p * 512 + k];
            int sl = v >> 7, dl = v & 127;
            float a = asL[sl] + adL[dl];
            a = (a > 0.f) ? a : 0.2f * a;
            atomicAdd(&S[((dl & 31) << 7) + sl], __expf(a));
        }
        for (unsigned int k = tid; k < novf; k += 512) {   // normally 0
            unsigned int v = ovfl[k];
            if (((v >> 5) & 3u) == (unsigned int)p) {
                int sl = v >> 7, dl = v & 127;
                float a = asL[sl] + adL[dl];
                a = (a > 0.f) ? a : 0.2f * a;
                atomicAdd(&S[((dl & 31) << 7) + sl], __expf(a));
            }
        }
        __syncthreads();
        // convert S[32][128] -> Ab rows 32p.. (bf16, stride 136), row sums,
        // rezero S for next pass. 16 threads per row; shfl tree.
        {
            int r = tid >> 4;
            int col = (tid & 15) << 3;
            float4 v0 = ((const float4*)S)[tid * 2];
            float4 v1 = ((const float4*)S)[tid * 2 + 1];
            ((float4*)S)[tid * 2] = make_float4(0.f, 0.f, 0.f, 0.f);
            ((float4*)S)[tid * 2 + 1] = make_float4(0.f, 0.f, 0.f, 0.f);
            float rs = v0.x + v0.y + v0.z + v0.w + v1.x + v1.y + v1.z + v1.w;
            bf16x8v pk = {f2bs(v0.x), f2bs(v0.y), f2bs(v0.z), f2bs(v0.w),
                          f2bs(v1.x), f2bs(v1.y), f2bs(v1.z), f2bs(v1.w)};
            *(bf16x8v*)&Ab[(32 * p + r) * 136 + col] = pk;
#pragma unroll
            for (int off = 1; off <= 8; off <<= 1) rs += __shfl_xor(rs, off);
            if ((tid & 15) == 0) dinv[32 * p + r] = 1.f / rs;
        }
        __syncthreads();
    }

    // ---- Final MFMA: wave w -> rows i0=w*16 (1 M-tile), 4 N-tiles, K=128 ----
    const int i0 = w * 16;
    f32x4 acc[4];
#pragma unroll
    for (int nt = 0; nt < 4; nt++) acc[nt] = (f32x4){0.f, 0.f, 0.f, 0.f};

#pragma unroll
    for (int ks = 0; ks < 4; ks++) {
        const int k0 = ks * 32 + quad * 8;
        bf16x8v a0 = *(const bf16x8v*)&Ab[(i0 + m) * 136 + k0];
#pragma unroll
        for (int nt = 0; nt < 4; nt++) {
            bf16x8v bfr = *(const bf16x8v*)&hT[(nt * 16 + m) * 136 + k0];
            acc[nt] = __builtin_amdgcn_mfma_f32_16x16x32_bf16(a0, bfr, acc[nt], 0, 0, 0);
        }
    }

    // epilogue: relu(acc*dinv + b1) . Wlin
    float dv[4];
#pragma unroll
    for (int r = 0; r < 4; r++) dv[r] = dinv[i0 + quad * 4 + r];

    float pacc = 0.f;
#pragma unroll
    for (int nt = 0; nt < 4; nt++) {
        float bb = b1[nt * 16 + m];
#pragma unroll
        for (int r = 0; r < 4; r++) {
            int il = i0 + quad * 4 + r;
            float v = acc[nt][r] * dv[r] + bb;
            v = v > 0.f ? v : 0.f;
            pacc += v * Wlin[il * 64 + nt * 16 + m];
        }
    }
#pragma unroll
    for (int off = 32; off; off >>= 1) pacc += __shfl_xor(pacc, off);

    __syncthreads();
    if (lane == 0) S[w] = pacc;
    __syncthreads();
    if (tid == 0) {
        float logit = S[0] + S[1] + S[2] + S[3] +
                      S[4] + S[5] + S[6] + S[7] + blin[0];
        out[g] = 1.f / (1.f + __expf(-logit));
    }
}

// ---------------------------------------------------------------------------
extern "C" void kernel_launch(void* const* d_in, const int* in_sizes, int n_in,
                              void* d_out, int out_size, void* d_ws, size_t ws_size,
                              hipStream_t stream) {
    (void)in_sizes; (void)n_in; (void)out_size; (void)ws_size;
    const float* x       = (const float*)d_in[0];
    const int*   ei      = (const int*)d_in[1];
    const float* W1      = (const float*)d_in[2];
    const float* att_src = (const float*)d_in[3];
    const float* att_dst = (const float*)d_in[4];
    const float* b1      = (const float*)d_in[5];
    const float* Wlin    = (const float*)d_in[6];
    const float* blin    = (const float*)d_in[7];
    float* out = (float*)d_out;

    char* ws = (char*)d_ws;
    bf16*           Bt      = (bf16*)ws;                        // 20,480 (pad 64K)
    unsigned int*   bccount = (unsigned int*)(ws + 65536);      // 256 KB
    unsigned int*   cbase   = (unsigned int*)(ws + 327680);     // 1,028 (pad 4K)
    unsigned int*   rbuf    = (unsigned int*)(ws + 331776);     // 8,388,608

    k0C1<<<296, 256, 0, stream>>>(W1, Bt, ei, bccount);
    kC3_scatter<<<256, 256, 0, stream>>>(ei, bccount, cbase, rbuf);
    k3_graph<<<G_, 512, 0, stream>>>(x, Bt, att_src, att_dst, rbuf, cbase,
                                     b1, Wlin, blin, out);
}